// Round 4
// baseline (490.840 us; speedup 1.0000x reference)
//
#include <hip/hip_runtime.h>

// PointPillarsScatter on MI355X.
// out[((b*C+c)*H+h)*W+w] = feat[owner(b, h*W+w), c], 0 where no owner.
// owner = argmax_p over pillars landing on the slot (last-wins overwrite
// semantics of sequential indexed assignment). Verified absmax 0.0 (r2,r3).
//
// ~11% of slots are occupied -> feature loads are PER-OWNER GUARDED so
// empty lanes issue no memory requests (exec-masked VMEM). Stores remain
// unconditional: full-wave contiguous 1 KiB NT bursts per channel plane.

#define B_  8
#define C_  64
#define H_  496
#define W_  432
#define HW_ (H_ * W_)          // 214272 (divisible by 4)

typedef int   v4i __attribute__((ext_vector_type(4)));
typedef float v4f __attribute__((ext_vector_type(4)));

// ---- pass 1: owner map = -1 --------------------------------------------
__global__ void pps_init_owner(int* __restrict__ owner, int n4) {
    int t = blockIdx.x * blockDim.x + threadIdx.x;
    if (t < n4) {
        v4i m1 = {-1, -1, -1, -1};
        __builtin_nontemporal_store(m1, (v4i*)owner + t);
    }
}

// ---- pass 2: last-wins slot ownership via atomicMax --------------------
__global__ void pps_scatter_owner(const int* __restrict__ coords,
                                  int* __restrict__ owner, int P) {
    int p = blockIdx.x * blockDim.x + threadIdx.x;
    if (p >= P) return;
    v4i c = ((const v4i*)coords)[p];         // (b, x, y, z)
    int idx = c.y * W_ + c.z;
    idx = min(max(idx, 0), HW_ - 1);         // clip, as in reference
    atomicMax(&owner[c.x * HW_ + idx], p);   // device-scope by default
}

// ---- pass 3: channel-loop gather, fuses zero-fill ----------------------
// One thread = 4 consecutive spatial positions x all 64 channels.
// Owner map read exactly once; occupied rows read by exactly one thread;
// empty lanes (89%) skip loads entirely via exec masking.
__global__ __launch_bounds__(256) void pps_gather(
        const float* __restrict__ feat,      // [P, 64]
        const int*   __restrict__ owner,     // [B*HW]
        float*       __restrict__ out,       // [B, C, H, W]
        int nquads) {                        // B*HW/4
    int t = blockIdx.x * blockDim.x + threadIdx.x;
    if (t >= nquads) return;
    unsigned pos    = (unsigned)t * 4u;      // b*HW + within, %4 == 0
    unsigned b      = pos / HW_;             // magic-mul
    unsigned within = pos - b * HW_;         // quads never cross b (HW_%4==0)

    v4i o = __builtin_nontemporal_load((const v4i*)&owner[pos]);
    const float* f0 = feat + (size_t)(unsigned)o.x * 64u;  // deref'd only if o>=0
    const float* f1 = feat + (size_t)(unsigned)o.y * 64u;
    const float* f2 = feat + (size_t)(unsigned)o.z * 64u;
    const float* f3 = feat + (size_t)(unsigned)o.w * 64u;
    const bool g0 = o.x >= 0, g1 = o.y >= 0, g2 = o.z >= 0, g3 = o.w >= 0;

    float* outp = out + (size_t)b * (C_ * HW_) + within;

    #pragma unroll 4
    for (int cc = 0; cc < C_; cc += 4) {
        v4f a  = {0.f, 0.f, 0.f, 0.f};
        v4f bq = {0.f, 0.f, 0.f, 0.f};
        v4f cq = {0.f, 0.f, 0.f, 0.f};
        v4f dq = {0.f, 0.f, 0.f, 0.f};
        if (g0) a  = *(const v4f*)(f0 + cc);   // exec-masked loads:
        if (g1) bq = *(const v4f*)(f1 + cc);   // inactive lanes issue no
        if (g2) cq = *(const v4f*)(f2 + cc);   // memory requests
        if (g3) dq = *(const v4f*)(f3 + cc);
        // 4x4 transpose: channel (cc+j) gets lane-quad {a[j],bq[j],cq[j],dq[j]}
        v4f w0 = {a.x, bq.x, cq.x, dq.x};
        v4f w1 = {a.y, bq.y, cq.y, dq.y};
        v4f w2 = {a.z, bq.z, cq.z, dq.z};
        v4f w3 = {a.w, bq.w, cq.w, dq.w};
        __builtin_nontemporal_store(w0, (v4f*)(outp + (size_t)(cc + 0) * HW_));
        __builtin_nontemporal_store(w1, (v4f*)(outp + (size_t)(cc + 1) * HW_));
        __builtin_nontemporal_store(w2, (v4f*)(outp + (size_t)(cc + 2) * HW_));
        __builtin_nontemporal_store(w3, (v4f*)(outp + (size_t)(cc + 3) * HW_));
    }
}

extern "C" void kernel_launch(void* const* d_in, const int* in_sizes, int n_in,
                              void* d_out, int out_size, void* d_ws, size_t ws_size,
                              hipStream_t stream) {
    const float* feat   = (const float*)d_in[0];   // [P,64] fp32
    const int*   coords = (const int*)d_in[1];     // [P,4] int32
    float*       out    = (float*)d_out;           // [8,64,496,432] fp32
    int*         owner  = (int*)d_ws;              // B*HW ints = 6.86 MB

    const int P = in_sizes[1] / 4;

    // pass 1: owner = -1
    const int n_owner  = B_ * HW_;                 // 1,714,176 (%4 == 0)
    const int n4_owner = n_owner / 4;
    pps_init_owner<<<(n4_owner + 255) / 256, 256, 0, stream>>>(owner, n4_owner);

    // pass 2: 200k atomicMax
    pps_scatter_owner<<<(P + 255) / 256, 256, 0, stream>>>(coords, owner, P);

    // pass 3: one thread per spatial quad, loops all 64 channels
    const int nquads = (B_ * HW_) / 4;             // 428,544
    pps_gather<<<(nquads + 255) / 256, 256, 0, stream>>>(feat, owner, out, nquads);
}